// Round 8
// baseline (149.902 us; speedup 1.0000x reference)
//
#include <hip/hip_runtime.h>
#include <hip/hip_fp16.h>

// GraphSAGE 2-layer. CSR via bucketed two-phase build (edge-parallel, XCD-local
// csr writes), wave-gather aggregation, fp16 MFMA GEMMs (fp32 accum).
// out = SAGE2( relu( SAGE1(x) ) ), SAGE(x) = meanagg(x)@W_l + x@W_r + b
// Layer 2 linearity: meanagg(h)@W2_l == meanagg(h@W2_l) -> gather 64 vals/edge.
// Requires N <= 65536 (nper<=256, src fits in u32>>8 packing). N=50000 here.
// NOTE: this is the verified round-5 structure (passed, 149us). The round-6
// LDS-accumulated-agg rewrite failed with a deterministic bit-identical error
// twice and was abandoned. Only launch-count reductions applied here.

typedef _Float16 half8 __attribute__((ext_vector_type(8)));
typedef float floatx4 __attribute__((ext_vector_type(4)));

#define NB 256        // buckets
#define PA 320        // partition phase-A blocks

// ---------- fused: fp16 convert + weight packing + degree count ----------
// Ah row (256 halves): [0:128] = inv*meanagg (by agg128h), [128:256] = fp16(x)
// Bp layout: Bp[((kt*8+nrep)*64+lane)*8+j] = B[kt*32+(lane>>4)*8+j][nrep*16+(lane&15)]
__global__ __launch_bounds__(256) void prep_deg_kernel(const float* __restrict__ x,
                                                       const float* __restrict__ W1l, const float* __restrict__ W1r,
                                                       const float* __restrict__ W2l, const float* __restrict__ W2r,
                                                       _Float16* __restrict__ Ah,
                                                       _Float16* __restrict__ Bp1, _Float16* __restrict__ Bp2,
                                                       const int* __restrict__ dst, int* __restrict__ degi,
                                                       int N, int E) {
    int nconv = (N * 64 + 255) / 256;
    int b = blockIdx.x;
    int tid = threadIdx.x;
    if (b < nconv) {
        int i = b * 256 + tid;
        if (i < N * 64) {
            int row = i >> 6, c = i & 63;
            float2 v = ((const float2*)x)[(size_t)row * 64 + c];
            __half2 h2 = __floats2half2_rn(v.x, v.y);
            *(__half2*)(Ah + (size_t)row * 256 + 128 + c * 2) = h2;
        }
    } else if (b < nconv + 128) {
        int t = (b - nconv) * 256 + tid;   // 32768 total
        int j = t & 7, lane = (t >> 3) & 63, nrep = (t >> 9) & 7, kt = t >> 12;
        int k = kt * 32 + ((lane >> 4) * 8) + j;
        int col = nrep * 16 + (lane & 15);
        float v = (k < 128) ? W1l[k * 128 + col] : W1r[(k - 128) * 128 + col];
        Bp1[t] = (_Float16)v;
    } else if (b < nconv + 192) {
        int t = (b - nconv - 128) * 256 + tid;   // 16384 total
        int j = t & 7, lane = (t >> 3) & 63, nrep = (t >> 9) & 7, kt = t >> 12;
        int k = kt * 32 + ((lane >> 4) * 8) + j;
        int col = nrep * 16 + (lane & 15);
        float v = (col < 64) ? W2l[k * 64 + col] : W2r[k * 64 + (col - 64)];
        Bp2[t] = (_Float16)v;
    } else {
        int i = (b - nconv - 192) * 256 + tid;   // over E/4 int4
        int E4 = E >> 2;
        if (i < E4) {
            int4 d = ((const int4*)dst)[i];
            atomicAdd(&degi[d.x], 1);
            atomicAdd(&degi[d.y], 1);
            atomicAdd(&degi[d.z], 1);
            atomicAdd(&degi[d.w], 1);
        }
        if (i == 0) {
            for (int e = E4 << 2; e < E; ++e) atomicAdd(&degi[dst[e]], 1);
        }
    }
}

// ---------- scans ----------
__global__ __launch_bounds__(256) void scan_pass1(const int* __restrict__ deg, int* __restrict__ incl,
                                                  int* __restrict__ bsum, int N) {
    int tid = threadIdx.x;
    int i = blockIdx.x * 256 + tid;
    int v = (i < N) ? deg[i] : 0;
    int lane = tid & 63, wid = tid >> 6;
    int s = v;
#pragma unroll
    for (int off = 1; off < 64; off <<= 1) { int t = __shfl_up(s, off); if (lane >= off) s += t; }
    __shared__ int ws[4], wo[4];
    if (lane == 63) ws[wid] = s;
    __syncthreads();
    if (tid == 0) { int a = 0; for (int w = 0; w < 4; ++w) { wo[w] = a; a += ws[w]; } bsum[blockIdx.x] = a; }
    __syncthreads();
    s += wo[wid];
    if (i < N) incl[i] = s;
}

// each block redundantly scans bsum (nblk<=256) for its own offset, then
// writes rp[i+1], inv, and bucket cursors (bcur[k] = rp[k*nper]) in one pass
__global__ __launch_bounds__(256) void scan_pass3f(const int* __restrict__ incl, const int* __restrict__ bsum,
                                                   const int* __restrict__ degi,
                                                   int* __restrict__ rp, float* __restrict__ inv,
                                                   int* __restrict__ bcur, int N, int nper, int nblk) {
    __shared__ int sx[256];
    int tid = threadIdx.x;
    int v = (tid < nblk) ? bsum[tid] : 0;
    int lane = tid & 63, wid = tid >> 6;
    int s = v;
#pragma unroll
    for (int off = 1; off < 64; off <<= 1) { int t = __shfl_up(s, off); if (lane >= off) s += t; }
    __shared__ int ws[4], wo[4];
    if (lane == 63) ws[wid] = s;
    __syncthreads();
    if (tid == 0) { int a = 0; for (int w = 0; w < 4; ++w) { wo[w] = a; a += ws[w]; } }
    __syncthreads();
    sx[tid] = s + wo[wid] - v;   // exclusive prefix of bsum
    __syncthreads();
    int boffv = sx[blockIdx.x];
    int i = blockIdx.x * 256 + tid;
    if (i < N) {
        int r = boffv + incl[i];
        rp[i + 1] = r;
        inv[i] = 1.0f / fmaxf((float)degi[i], 1.0f);
        if (i == 0) { rp[0] = 0; bcur[0] = 0; }
        int ip1 = i + 1;
        if (ip1 % nper == 0 && ip1 / nper < NB) bcur[ip1 / nper] = r;
    }
}

// ---------- phase A: partition edges into bucket segments ----------
// bek[pos] = (src<<8) | (dst - bucket*nper); per-(block,bucket) runs contiguous.
__global__ __launch_bounds__(256) void partA_kernel(const int* __restrict__ src, const int* __restrict__ dst,
                                                    int* __restrict__ bcur, unsigned int* __restrict__ bek,
                                                    int E, int nper) {
    __shared__ int cnt[NB], base[NB], cur[NB];
    int tid = threadIdx.x;
    int chunk = (E + PA - 1) / PA;
    int e0 = blockIdx.x * chunk;
    int e1 = min(e0 + chunk, E);
    cnt[tid] = 0;
    cur[tid] = 0;
    __syncthreads();
    for (int e = e0 + tid; e < e1; e += 256) {
        int d = dst[e];
        atomicAdd(&cnt[d / nper], 1);
    }
    __syncthreads();
    int c = cnt[tid];
    base[tid] = (c > 0) ? atomicAdd(&bcur[tid], c) : 0;
    __syncthreads();
    for (int e = e0 + tid; e < e1; e += 256) {
        int d = dst[e];
        int b = d / nper;
        int pos = base[b] + atomicAdd(&cur[b], 1);
        bek[pos] = ((unsigned int)src[e] << 8) | (unsigned int)(d - b * nper);
    }
}

// ---------- phase B: within-bucket scatter to csr (block-exclusive window) ----------
__global__ __launch_bounds__(256) void partB_kernel(const unsigned int* __restrict__ bek,
                                                    const int* __restrict__ rp, int* __restrict__ csr,
                                                    int N, int nper) {
    __shared__ int rps[256], cur[256];
    int k = blockIdx.x;
    int lo = k * nper;
    int hi = min(lo + nper, N);
    int cntN = hi - lo;
    if (cntN <= 0) return;
    int tid = threadIdx.x;
    if (tid < cntN) { rps[tid] = rp[lo + tid]; cur[tid] = 0; }
    __syncthreads();
    int ebeg = rp[lo], eend = rp[hi];
    for (int j = ebeg + tid; j < eend; j += 256) {
        unsigned int u = bek[j];
        int loc = (int)(u & 0xffu);
        int s = (int)(u >> 8);
        int pos = rps[loc] + atomicAdd(&cur[loc], 1);
        csr[pos] = s;
    }
}

// ---------- gather aggregation (fp16 payload, fp32 accum, 8-deep ILP) ----------
__global__ __launch_bounds__(256) void agg128h_kernel(const int* __restrict__ rp, const int* __restrict__ ci,
                                                      _Float16* __restrict__ Ah,
                                                      const float* __restrict__ inv, int N) {
    int node = (blockIdx.x * 256 + threadIdx.x) >> 6;
    int lane = threadIdx.x & 63;
    if (node >= N) return;
    int beg = rp[node], end = rp[node + 1];
    const uint* xu = (const uint*)Ah;   // half2 units; row = 128 units, x-part at +64
    float2 acc = make_float2(0.f, 0.f);
    for (int base = beg; base < end; base += 64) {
        int idx = base + lane;
        int sv = (idx < end) ? ci[idx] : 0;
        int cnt = min(64, end - base);
        int j = 0;
        for (; j + 8 <= cnt; j += 8) {
            uint u[8];
#pragma unroll
            for (int w = 0; w < 8; ++w) {
                int s = __shfl(sv, j + w);
                u[w] = xu[(size_t)s * 128 + 64 + lane];
            }
#pragma unroll
            for (int w = 0; w < 8; ++w) {
                float2 f = __half22float2(*(const __half2*)&u[w]);
                acc.x += f.x; acc.y += f.y;
            }
        }
        for (; j + 4 <= cnt; j += 4) {
            uint u[4];
#pragma unroll
            for (int w = 0; w < 4; ++w) {
                int s = __shfl(sv, j + w);
                u[w] = xu[(size_t)s * 128 + 64 + lane];
            }
#pragma unroll
            for (int w = 0; w < 4; ++w) {
                float2 f = __half22float2(*(const __half2*)&u[w]);
                acc.x += f.x; acc.y += f.y;
            }
        }
        for (; j < cnt; ++j) {
            int s = __shfl(sv, j);
            uint u = xu[(size_t)s * 128 + 64 + lane];
            float2 f = __half22float2(*(const __half2*)&u);
            acc.x += f.x; acc.y += f.y;
        }
    }
    float iv = inv[node];
    __half2 o = __floats2half2_rn(acc.x * iv, acc.y * iv);
    ((uint*)Ah)[(size_t)node * 128 + lane] = *(const uint*)&o;
}

__global__ __launch_bounds__(256) void agg64h_kernel(const int* __restrict__ rp, const int* __restrict__ ci,
                                                     const _Float16* __restrict__ hl,
                                                     const float* __restrict__ inv,
                                                     float* __restrict__ out, int N) {
    int node = (blockIdx.x * 256 + threadIdx.x) >> 5;
    int sl = threadIdx.x & 31;
    if (node >= N) return;
    int beg = rp[node], end = rp[node + 1];
    const uint* hu = (const uint*)hl;   // 32 half2 per row
    float2 acc = make_float2(0.f, 0.f);
    for (int base = beg; base < end; base += 32) {
        int idx = base + sl;
        int sv = (idx < end) ? ci[idx] : 0;
        int cnt = min(32, end - base);
        int j = 0;
        for (; j + 8 <= cnt; j += 8) {
            uint u[8];
#pragma unroll
            for (int w = 0; w < 8; ++w) {
                int s = __shfl(sv, j + w, 32);
                u[w] = hu[(size_t)s * 32 + sl];
            }
#pragma unroll
            for (int w = 0; w < 8; ++w) {
                float2 f = __half22float2(*(const __half2*)&u[w]);
                acc.x += f.x; acc.y += f.y;
            }
        }
        for (; j + 4 <= cnt; j += 4) {
            uint u[4];
#pragma unroll
            for (int w = 0; w < 4; ++w) {
                int s = __shfl(sv, j + w, 32);
                u[w] = hu[(size_t)s * 32 + sl];
            }
#pragma unroll
            for (int w = 0; w < 4; ++w) {
                float2 f = __half22float2(*(const __half2*)&u[w]);
                acc.x += f.x; acc.y += f.y;
            }
        }
        for (; j < cnt; ++j) {
            int s = __shfl(sv, j, 32);
            uint u = hu[(size_t)s * 32 + sl];
            float2 f = __half22float2(*(const __half2*)&u);
            acc.x += f.x; acc.y += f.y;
        }
    }
    float iv = inv[node];
    float2* op = (float2*)(out + (size_t)node * 64 + sl * 2);
    float2 cur = *op;
    cur.x += iv * acc.x;
    cur.y += iv * acc.y;
    *op = cur;
}

// ---------- MFMA GEMMs ----------
__global__ __launch_bounds__(256) void gemm1_mfma(const _Float16* __restrict__ Ah,
                                                  const _Float16* __restrict__ Bp,
                                                  const float* __restrict__ b1,
                                                  _Float16* __restrict__ hh, int N) {
    int wid = threadIdx.x >> 6, lane = threadIdx.x & 63;
    int r = lane & 15, q = lane >> 4;
    int rowbase = blockIdx.x * 128 + wid * 32;
    size_t ra = (size_t)min(rowbase + r, N - 1);
    size_t rb = (size_t)min(rowbase + 16 + r, N - 1);
    const half8* B8 = (const half8*)Bp;

    floatx4 acc[2][8];
#pragma unroll
    for (int m = 0; m < 2; ++m)
#pragma unroll
        for (int n = 0; n < 8; ++n) acc[m][n] = (floatx4){0.f, 0.f, 0.f, 0.f};

#pragma unroll
    for (int kt = 0; kt < 8; ++kt) {
        int k0 = kt * 32 + q * 8;
        half8 a0 = *(const half8*)(Ah + ra * 256 + k0);
        half8 a1 = *(const half8*)(Ah + rb * 256 + k0);
#pragma unroll
        for (int n = 0; n < 8; ++n) {
            half8 bf = B8[(kt * 8 + n) * 64 + lane];
            acc[0][n] = __builtin_amdgcn_mfma_f32_16x16x32_f16(a0, bf, acc[0][n], 0, 0, 0);
            acc[1][n] = __builtin_amdgcn_mfma_f32_16x16x32_f16(a1, bf, acc[1][n], 0, 0, 0);
        }
    }
    float bias[8];
#pragma unroll
    for (int n = 0; n < 8; ++n) bias[n] = b1[n * 16 + r];
#pragma unroll
    for (int m = 0; m < 2; ++m)
#pragma unroll
        for (int reg = 0; reg < 4; ++reg) {
            int row = rowbase + m * 16 + q * 4 + reg;
            if (row < N) {
                _Float16* p = hh + (size_t)row * 128 + r;
#pragma unroll
                for (int n = 0; n < 8; ++n)
                    p[n * 16] = (_Float16)fmaxf(acc[m][n][reg] + bias[n], 0.f);
            }
        }
}

__global__ __launch_bounds__(256) void gemm2_mfma(const _Float16* __restrict__ hh,
                                                  const _Float16* __restrict__ Bp,
                                                  const float* __restrict__ b2,
                                                  _Float16* __restrict__ hl,
                                                  float* __restrict__ outp, int N) {
    int wid = threadIdx.x >> 6, lane = threadIdx.x & 63;
    int r = lane & 15, q = lane >> 4;
    int rowbase = blockIdx.x * 128 + wid * 32;
    size_t ra = (size_t)min(rowbase + r, N - 1);
    size_t rb = (size_t)min(rowbase + 16 + r, N - 1);
    const half8* B8 = (const half8*)Bp;

    floatx4 acc[2][8];
#pragma unroll
    for (int m = 0; m < 2; ++m)
#pragma unroll
        for (int n = 0; n < 8; ++n) acc[m][n] = (floatx4){0.f, 0.f, 0.f, 0.f};

#pragma unroll
    for (int kt = 0; kt < 4; ++kt) {
        int k0 = kt * 32 + q * 8;
        half8 a0 = *(const half8*)(hh + ra * 128 + k0);
        half8 a1 = *(const half8*)(hh + rb * 128 + k0);
#pragma unroll
        for (int n = 0; n < 8; ++n) {
            half8 bf = B8[(kt * 8 + n) * 64 + lane];
            acc[0][n] = __builtin_amdgcn_mfma_f32_16x16x32_f16(a0, bf, acc[0][n], 0, 0, 0);
            acc[1][n] = __builtin_amdgcn_mfma_f32_16x16x32_f16(a1, bf, acc[1][n], 0, 0, 0);
        }
    }
    float bias[4];
#pragma unroll
    for (int n = 0; n < 4; ++n) bias[n] = b2[n * 16 + r];
#pragma unroll
    for (int m = 0; m < 2; ++m)
#pragma unroll
        for (int reg = 0; reg < 4; ++reg) {
            int row = rowbase + m * 16 + q * 4 + reg;
            if (row < N) {
                _Float16* ph = hl + (size_t)row * 64 + r;
                float* po = outp + (size_t)row * 64 + r;
#pragma unroll
                for (int n = 0; n < 4; ++n)
                    ph[n * 16] = (_Float16)acc[m][n][reg];
#pragma unroll
                for (int n = 0; n < 4; ++n)
                    po[n * 16] = acc[m][n + 4][reg] + bias[n];
            }
        }
}

extern "C" void kernel_launch(void* const* d_in, const int* in_sizes, int n_in,
                              void* d_out, int out_size, void* d_ws, size_t ws_size,
                              hipStream_t stream) {
    const float* x   = (const float*)d_in[0];
    const int*   ei  = (const int*)d_in[1];
    const float* W1l = (const float*)d_in[2];
    const float* W1r = (const float*)d_in[3];
    const float* b1  = (const float*)d_in[4];
    const float* W2l = (const float*)d_in[5];
    const float* W2r = (const float*)d_in[6];
    const float* b2  = (const float*)d_in[7];
    float* out = (float*)d_out;

    const int N = in_sizes[0] / 128;   // 50000
    const int E = in_sizes[1] / 2;     // 640000
    const int* srcv = ei;
    const int* dstv = ei + E;
    const int nper = (N + NB - 1) / NB;   // 196 (requires <= 256)

    // workspace layout
    _Float16* Ah  = (_Float16*)d_ws;                      // N*256 halves
    _Float16* hh  = Ah + (size_t)N * 256;                 // N*128 halves
    _Float16* hl  = hh + (size_t)N * 128;                 // N*64 halves
    _Float16* Bp1 = hl + (size_t)N * 64;                  // 32768 halves
    _Float16* Bp2 = Bp1 + 32768;                          // 16384 halves
    float* inv  = (float*)(Bp2 + 16384);                  // N floats
    int*   rp   = (int*)(inv + N);                        // N+1
    int*   degi = rp + (N + 1);                           // N
    int*   incl = degi + N;                               // N
    int*   csr  = incl + N;                               // E
    unsigned int* bek = (unsigned int*)(csr + E);         // E
    int*   bsum = (int*)(bek + E);                        // 256
    int*   bcur = bsum + 256;                             // NB

    const int nsblk = (N + 255) / 256;                    // 196 (<= 256)

    hipMemsetAsync(degi, 0, (size_t)N * sizeof(int), stream);

    int nconv = (N * 64 + 255) / 256;                     // 12500
    int ndeg = ((E >> 2) + 255) / 256;                    // 625
    prep_deg_kernel<<<nconv + 192 + ndeg, 256, 0, stream>>>(x, W1l, W1r, W2l, W2r,
                                                            Ah, Bp1, Bp2, dstv, degi, N, E);

    scan_pass1<<<nsblk, 256, 0, stream>>>(degi, incl, bsum, N);
    scan_pass3f<<<nsblk, 256, 0, stream>>>(incl, bsum, degi, rp, inv, bcur, N, nper, nsblk);

    partA_kernel<<<PA, 256, 0, stream>>>(srcv, dstv, bcur, bek, E, nper);
    partB_kernel<<<NB, 256, 0, stream>>>(bek, rp, csr, N, nper);

    // layer 1
    agg128h_kernel<<<(N * 64 + 255) / 256, 256, 0, stream>>>(rp, csr, Ah, inv, N);
    int nb = (N + 127) / 128;
    gemm1_mfma<<<nb, 256, 0, stream>>>(Ah, Bp1, b1, hh, N);

    // layer 2
    gemm2_mfma<<<nb, 256, 0, stream>>>(hh, Bp2, b2, hl, out, N);
    agg64h_kernel<<<(N * 32 + 255) / 256, 256, 0, stream>>>(rp, csr, hl, inv, out, N);
}

// Round 9
// 126.998 us; speedup vs baseline: 1.1803x; 1.1803x over previous
//
#include <hip/hip_runtime.h>
#include <hip/hip_fp16.h>

// GraphSAGE 2-layer. CSR via bucketed two-phase build; degrees + row-pointers
// derived IN-BUCKET with LDS counters (no global degree atomics, no N-wide
// scans). Wave-gather aggregation, fp16 MFMA GEMMs (fp32 accum).
// out = SAGE2( relu( SAGE1(x) ) ), SAGE(x) = meanagg(x)@W_l + x@W_r + b
// Layer 2 linearity: meanagg(h)@W2_l == meanagg(h@W2_l) -> gather 64 vals/edge.
// Requires N <= 65536 (nper<=256, src fits in u32>>8 packing). N=50000 here.

typedef _Float16 half8 __attribute__((ext_vector_type(8)));
typedef float floatx4 __attribute__((ext_vector_type(4)));

#define NB 256        // buckets
#define PA 320        // partition phase-A blocks
#define HB 320        // histogram chunks (fused into prep)

// ---------- fused: fp16 convert + weight packing + bucket histogram ----------
// Ah row (256 halves): [0:128] = inv*meanagg (by agg128h), [128:256] = fp16(x)
// Bp layout: Bp[((kt*8+nrep)*64+lane)*8+j] = B[kt*32+(lane>>4)*8+j][nrep*16+(lane&15)]
__global__ __launch_bounds__(256) void prep_hist_kernel(const float* __restrict__ x,
                                                        const float* __restrict__ W1l, const float* __restrict__ W1r,
                                                        const float* __restrict__ W2l, const float* __restrict__ W2r,
                                                        _Float16* __restrict__ Ah,
                                                        _Float16* __restrict__ Bp1, _Float16* __restrict__ Bp2,
                                                        const int* __restrict__ dst, int* __restrict__ ghist,
                                                        int N, int E, int nper) {
    __shared__ int lh[NB];
    int nconv = (N * 64 + 255) / 256;
    int b = blockIdx.x;
    int tid = threadIdx.x;
    if (b < nconv) {
        int i = b * 256 + tid;
        if (i < N * 64) {
            int row = i >> 6, c = i & 63;
            float2 v = ((const float2*)x)[(size_t)row * 64 + c];
            __half2 h2 = __floats2half2_rn(v.x, v.y);
            *(__half2*)(Ah + (size_t)row * 256 + 128 + c * 2) = h2;
        }
    } else if (b < nconv + 128) {
        int t = (b - nconv) * 256 + tid;   // 32768 total
        int j = t & 7, lane = (t >> 3) & 63, nrep = (t >> 9) & 7, kt = t >> 12;
        int k = kt * 32 + ((lane >> 4) * 8) + j;
        int col = nrep * 16 + (lane & 15);
        float v = (k < 128) ? W1l[k * 128 + col] : W1r[(k - 128) * 128 + col];
        Bp1[t] = (_Float16)v;
    } else if (b < nconv + 192) {
        int t = (b - nconv - 128) * 256 + tid;   // 16384 total
        int j = t & 7, lane = (t >> 3) & 63, nrep = (t >> 9) & 7, kt = t >> 12;
        int k = kt * 32 + ((lane >> 4) * 8) + j;
        int col = nrep * 16 + (lane & 15);
        float v = (col < 64) ? W2l[k * 64 + col] : W2r[k * 64 + (col - 64)];
        Bp2[t] = (_Float16)v;
    } else {
        // bucket histogram over a chunk of edges (LDS hist -> one global add/bin)
        int hb = b - nconv - 192;             // 0..HB-1
        lh[tid] = 0;
        __syncthreads();
        int chunk = (E + HB - 1) / HB;
        int e0 = hb * chunk, e1 = min(e0 + chunk, E);
        for (int e = e0 + tid; e < e1; e += 256) atomicAdd(&lh[dst[e] / nper], 1);
        __syncthreads();
        int c = lh[tid];
        if (c) atomicAdd(&ghist[tid], c);
    }
}

// ---------- exclusive scan of 256 bucket counts (single block) ----------
__global__ __launch_bounds__(256) void scan256_kernel(const int* __restrict__ ghist,
                                                      int* __restrict__ bbase, int* __restrict__ bcur) {
    int tid = threadIdx.x;
    int v = ghist[tid];
    int lane = tid & 63, wid = tid >> 6;
    int s = v;
#pragma unroll
    for (int off = 1; off < 64; off <<= 1) { int t = __shfl_up(s, off); if (lane >= off) s += t; }
    __shared__ int ws[4], wo[4];
    if (lane == 63) ws[wid] = s;
    __syncthreads();
    if (tid == 0) { int a = 0; for (int w = 0; w < 4; ++w) { wo[w] = a; a += ws[w]; } }
    __syncthreads();
    s += wo[wid];            // inclusive
    bbase[tid] = s - v;      // exclusive
    bcur[tid]  = s - v;
    if (tid == 255) bbase[NB] = s;   // == E
}

// ---------- phase A: partition edges into bucket segments (verified) ----------
// bek[pos] = (src<<8) | (dst - bucket*nper); per-(block,bucket) runs contiguous.
__global__ __launch_bounds__(256) void partA_kernel(const int* __restrict__ src, const int* __restrict__ dst,
                                                    int* __restrict__ bcur, unsigned int* __restrict__ bek,
                                                    int E, int nper) {
    __shared__ int cnt[NB], base[NB], cur[NB];
    int tid = threadIdx.x;
    int chunk = (E + PA - 1) / PA;
    int e0 = blockIdx.x * chunk;
    int e1 = min(e0 + chunk, E);
    cnt[tid] = 0;
    cur[tid] = 0;
    __syncthreads();
    for (int e = e0 + tid; e < e1; e += 256) {
        int d = dst[e];
        atomicAdd(&cnt[d / nper], 1);
    }
    __syncthreads();
    int c = cnt[tid];
    base[tid] = (c > 0) ? atomicAdd(&bcur[tid], c) : 0;
    __syncthreads();
    for (int e = e0 + tid; e < e1; e += 256) {
        int d = dst[e];
        int b = d / nper;
        int pos = base[b] + atomicAdd(&cur[b], 1);
        bek[pos] = ((unsigned int)src[e] << 8) | (unsigned int)(d - b * nper);
    }
}

// ---------- phase B: per-bucket degree count (LDS) + local scan -> rp/inv,
//            then within-bucket scatter to csr (block-exclusive window) ----------
__global__ __launch_bounds__(256) void partB2_kernel(const unsigned int* __restrict__ bek,
                                                     const int* __restrict__ bbase,
                                                     int* __restrict__ rp, float* __restrict__ inv,
                                                     int* __restrict__ csr, int N, int nper) {
    __shared__ int lcnt[256], excl[256], cur[256];
    __shared__ int ws[4], wo[4];
    int k = blockIdx.x;
    int lo = k * nper;
    int hi = min(lo + nper, N);
    int cntN = hi - lo;
    if (cntN <= 0) return;   // uniform per block
    int tid = threadIdx.x;
    lcnt[tid] = 0; cur[tid] = 0;
    __syncthreads();
    int ebeg = bbase[k], eend = bbase[k + 1];
    // pass 1: per-node degree within bucket
    for (int j = ebeg + tid; j < eend; j += 256)
        atomicAdd(&lcnt[bek[j] & 0xffu], 1);
    __syncthreads();
    // exclusive scan of lcnt[0..256) (locs >= cntN are zero)
    int v = lcnt[tid];
    int lane = tid & 63, wid = tid >> 6;
    int s = v;
#pragma unroll
    for (int off = 1; off < 64; off <<= 1) { int t = __shfl_up(s, off); if (lane >= off) s += t; }
    if (lane == 63) ws[wid] = s;
    __syncthreads();
    if (tid == 0) { int a = 0; for (int w = 0; w < 4; ++w) { wo[w] = a; a += ws[w]; } }
    __syncthreads();
    excl[tid] = s + wo[wid] - v;
    __syncthreads();
    // rp / inv (rp[lo+cntN] == eend; double-written by neighbor bucket, same value)
    if (tid <= cntN) {
        int node = lo + tid;
        if (node <= N) rp[node] = ebeg + excl[tid];
        if (tid < cntN) inv[node] = 1.0f / fmaxf((float)lcnt[tid], 1.0f);
    }
    // pass 2: scatter src ids into csr
    for (int j = ebeg + tid; j < eend; j += 256) {
        unsigned int u = bek[j];
        int loc = (int)(u & 0xffu);
        int pos = ebeg + excl[loc] + atomicAdd(&cur[loc], 1);
        csr[pos] = (int)(u >> 8);
    }
}

// ---------- gather aggregation (fp16 payload, fp32 accum, 8-deep ILP) ----------
__global__ __launch_bounds__(256) void agg128h_kernel(const int* __restrict__ rp, const int* __restrict__ ci,
                                                      _Float16* __restrict__ Ah,
                                                      const float* __restrict__ inv, int N) {
    int node = (blockIdx.x * 256 + threadIdx.x) >> 6;
    int lane = threadIdx.x & 63;
    if (node >= N) return;
    int beg = rp[node], end = rp[node + 1];
    const uint* xu = (const uint*)Ah;   // half2 units; row = 128 units, x-part at +64
    float2 acc = make_float2(0.f, 0.f);
    for (int base = beg; base < end; base += 64) {
        int idx = base + lane;
        int sv = (idx < end) ? ci[idx] : 0;
        int cnt = min(64, end - base);
        int j = 0;
        for (; j + 8 <= cnt; j += 8) {
            uint u[8];
#pragma unroll
            for (int w = 0; w < 8; ++w) {
                int s = __shfl(sv, j + w);
                u[w] = xu[(size_t)s * 128 + 64 + lane];
            }
#pragma unroll
            for (int w = 0; w < 8; ++w) {
                float2 f = __half22float2(*(const __half2*)&u[w]);
                acc.x += f.x; acc.y += f.y;
            }
        }
        for (; j + 4 <= cnt; j += 4) {
            uint u[4];
#pragma unroll
            for (int w = 0; w < 4; ++w) {
                int s = __shfl(sv, j + w);
                u[w] = xu[(size_t)s * 128 + 64 + lane];
            }
#pragma unroll
            for (int w = 0; w < 4; ++w) {
                float2 f = __half22float2(*(const __half2*)&u[w]);
                acc.x += f.x; acc.y += f.y;
            }
        }
        for (; j < cnt; ++j) {
            int s = __shfl(sv, j);
            uint u = xu[(size_t)s * 128 + 64 + lane];
            float2 f = __half22float2(*(const __half2*)&u);
            acc.x += f.x; acc.y += f.y;
        }
    }
    float iv = inv[node];
    __half2 o = __floats2half2_rn(acc.x * iv, acc.y * iv);
    ((uint*)Ah)[(size_t)node * 128 + lane] = *(const uint*)&o;
}

__global__ __launch_bounds__(256) void agg64h_kernel(const int* __restrict__ rp, const int* __restrict__ ci,
                                                     const _Float16* __restrict__ hl,
                                                     const float* __restrict__ inv,
                                                     float* __restrict__ out, int N) {
    int node = (blockIdx.x * 256 + threadIdx.x) >> 5;
    int sl = threadIdx.x & 31;
    if (node >= N) return;
    int beg = rp[node], end = rp[node + 1];
    const uint* hu = (const uint*)hl;   // 32 half2 per row
    float2 acc = make_float2(0.f, 0.f);
    for (int base = beg; base < end; base += 32) {
        int idx = base + sl;
        int sv = (idx < end) ? ci[idx] : 0;
        int cnt = min(32, end - base);
        int j = 0;
        for (; j + 8 <= cnt; j += 8) {
            uint u[8];
#pragma unroll
            for (int w = 0; w < 8; ++w) {
                int s = __shfl(sv, j + w, 32);
                u[w] = hu[(size_t)s * 32 + sl];
            }
#pragma unroll
            for (int w = 0; w < 8; ++w) {
                float2 f = __half22float2(*(const __half2*)&u[w]);
                acc.x += f.x; acc.y += f.y;
            }
        }
        for (; j + 4 <= cnt; j += 4) {
            uint u[4];
#pragma unroll
            for (int w = 0; w < 4; ++w) {
                int s = __shfl(sv, j + w, 32);
                u[w] = hu[(size_t)s * 32 + sl];
            }
#pragma unroll
            for (int w = 0; w < 4; ++w) {
                float2 f = __half22float2(*(const __half2*)&u[w]);
                acc.x += f.x; acc.y += f.y;
            }
        }
        for (; j < cnt; ++j) {
            int s = __shfl(sv, j, 32);
            uint u = hu[(size_t)s * 32 + sl];
            float2 f = __half22float2(*(const __half2*)&u);
            acc.x += f.x; acc.y += f.y;
        }
    }
    float iv = inv[node];
    float2* op = (float2*)(out + (size_t)node * 64 + sl * 2);
    float2 cur = *op;
    cur.x += iv * acc.x;
    cur.y += iv * acc.y;
    *op = cur;
}

// ---------- MFMA GEMMs ----------
__global__ __launch_bounds__(256) void gemm1_mfma(const _Float16* __restrict__ Ah,
                                                  const _Float16* __restrict__ Bp,
                                                  const float* __restrict__ b1,
                                                  _Float16* __restrict__ hh, int N) {
    int wid = threadIdx.x >> 6, lane = threadIdx.x & 63;
    int r = lane & 15, q = lane >> 4;
    int rowbase = blockIdx.x * 128 + wid * 32;
    size_t ra = (size_t)min(rowbase + r, N - 1);
    size_t rb = (size_t)min(rowbase + 16 + r, N - 1);
    const half8* B8 = (const half8*)Bp;

    floatx4 acc[2][8];
#pragma unroll
    for (int m = 0; m < 2; ++m)
#pragma unroll
        for (int n = 0; n < 8; ++n) acc[m][n] = (floatx4){0.f, 0.f, 0.f, 0.f};

#pragma unroll
    for (int kt = 0; kt < 8; ++kt) {
        int k0 = kt * 32 + q * 8;
        half8 a0 = *(const half8*)(Ah + ra * 256 + k0);
        half8 a1 = *(const half8*)(Ah + rb * 256 + k0);
#pragma unroll
        for (int n = 0; n < 8; ++n) {
            half8 bf = B8[(kt * 8 + n) * 64 + lane];
            acc[0][n] = __builtin_amdgcn_mfma_f32_16x16x32_f16(a0, bf, acc[0][n], 0, 0, 0);
            acc[1][n] = __builtin_amdgcn_mfma_f32_16x16x32_f16(a1, bf, acc[1][n], 0, 0, 0);
        }
    }
    float bias[8];
#pragma unroll
    for (int n = 0; n < 8; ++n) bias[n] = b1[n * 16 + r];
#pragma unroll
    for (int m = 0; m < 2; ++m)
#pragma unroll
        for (int reg = 0; reg < 4; ++reg) {
            int row = rowbase + m * 16 + q * 4 + reg;
            if (row < N) {
                _Float16* p = hh + (size_t)row * 128 + r;
#pragma unroll
                for (int n = 0; n < 8; ++n)
                    p[n * 16] = (_Float16)fmaxf(acc[m][n][reg] + bias[n], 0.f);
            }
        }
}

__global__ __launch_bounds__(256) void gemm2_mfma(const _Float16* __restrict__ hh,
                                                  const _Float16* __restrict__ Bp,
                                                  const float* __restrict__ b2,
                                                  _Float16* __restrict__ hl,
                                                  float* __restrict__ outp, int N) {
    int wid = threadIdx.x >> 6, lane = threadIdx.x & 63;
    int r = lane & 15, q = lane >> 4;
    int rowbase = blockIdx.x * 128 + wid * 32;
    size_t ra = (size_t)min(rowbase + r, N - 1);
    size_t rb = (size_t)min(rowbase + 16 + r, N - 1);
    const half8* B8 = (const half8*)Bp;

    floatx4 acc[2][8];
#pragma unroll
    for (int m = 0; m < 2; ++m)
#pragma unroll
        for (int n = 0; n < 8; ++n) acc[m][n] = (floatx4){0.f, 0.f, 0.f, 0.f};

#pragma unroll
    for (int kt = 0; kt < 4; ++kt) {
        int k0 = kt * 32 + q * 8;
        half8 a0 = *(const half8*)(hh + ra * 128 + k0);
        half8 a1 = *(const half8*)(hh + rb * 128 + k0);
#pragma unroll
        for (int n = 0; n < 8; ++n) {
            half8 bf = B8[(kt * 8 + n) * 64 + lane];
            acc[0][n] = __builtin_amdgcn_mfma_f32_16x16x32_f16(a0, bf, acc[0][n], 0, 0, 0);
            acc[1][n] = __builtin_amdgcn_mfma_f32_16x16x32_f16(a1, bf, acc[1][n], 0, 0, 0);
        }
    }
    float bias[4];
#pragma unroll
    for (int n = 0; n < 4; ++n) bias[n] = b2[n * 16 + r];
#pragma unroll
    for (int m = 0; m < 2; ++m)
#pragma unroll
        for (int reg = 0; reg < 4; ++reg) {
            int row = rowbase + m * 16 + q * 4 + reg;
            if (row < N) {
                _Float16* ph = hl + (size_t)row * 64 + r;
                float* po = outp + (size_t)row * 64 + r;
#pragma unroll
                for (int n = 0; n < 4; ++n)
                    ph[n * 16] = (_Float16)acc[m][n][reg];
#pragma unroll
                for (int n = 0; n < 4; ++n)
                    po[n * 16] = acc[m][n + 4][reg] + bias[n];
            }
        }
}

extern "C" void kernel_launch(void* const* d_in, const int* in_sizes, int n_in,
                              void* d_out, int out_size, void* d_ws, size_t ws_size,
                              hipStream_t stream) {
    const float* x   = (const float*)d_in[0];
    const int*   ei  = (const int*)d_in[1];
    const float* W1l = (const float*)d_in[2];
    const float* W1r = (const float*)d_in[3];
    const float* b1  = (const float*)d_in[4];
    const float* W2l = (const float*)d_in[5];
    const float* W2r = (const float*)d_in[6];
    const float* b2  = (const float*)d_in[7];
    float* out = (float*)d_out;

    const int N = in_sizes[0] / 128;   // 50000
    const int E = in_sizes[1] / 2;     // 640000
    const int* srcv = ei;
    const int* dstv = ei + E;
    const int nper = (N + NB - 1) / NB;   // 196 (requires <= 256)

    // workspace layout
    _Float16* Ah  = (_Float16*)d_ws;                      // N*256 halves
    _Float16* hh  = Ah + (size_t)N * 256;                 // N*128 halves
    _Float16* hl  = hh + (size_t)N * 128;                 // N*64 halves
    _Float16* Bp1 = hl + (size_t)N * 64;                  // 32768 halves
    _Float16* Bp2 = Bp1 + 32768;                          // 16384 halves
    float* inv  = (float*)(Bp2 + 16384);                  // N floats
    int*   rp   = (int*)(inv + N);                        // N+1
    int*   csr  = rp + (N + 1);                           // E
    unsigned int* bek = (unsigned int*)(csr + E);         // E
    int*   ghist = (int*)(bek + E);                       // NB
    int*   bbase = ghist + NB;                            // NB+1
    int*   bcur  = bbase + (NB + 1);                      // NB

    hipMemsetAsync(ghist, 0, (size_t)NB * sizeof(int), stream);

    int nconv = (N * 64 + 255) / 256;                     // 12500
    prep_hist_kernel<<<nconv + 192 + HB, 256, 0, stream>>>(x, W1l, W1r, W2l, W2r,
                                                           Ah, Bp1, Bp2, dstv, ghist, N, E, nper);

    scan256_kernel<<<1, 256, 0, stream>>>(ghist, bbase, bcur);
    partA_kernel<<<PA, 256, 0, stream>>>(srcv, dstv, bcur, bek, E, nper);
    partB2_kernel<<<NB, 256, 0, stream>>>(bek, bbase, rp, inv, csr, N, nper);

    // layer 1
    agg128h_kernel<<<(N * 64 + 255) / 256, 256, 0, stream>>>(rp, csr, Ah, inv, N);
    int nb = (N + 127) / 128;
    gemm1_mfma<<<nb, 256, 0, stream>>>(Ah, Bp1, b1, hh, N);

    // layer 2
    gemm2_mfma<<<nb, 256, 0, stream>>>(hh, Bp2, b2, hl, out, N);
    agg64h_kernel<<<(N * 32 + 255) / 256, 256, 0, stream>>>(rp, csr, hl, inv, out, N);
}

// Round 11
// 124.143 us; speedup vs baseline: 1.2075x; 1.0230x over previous
//
#include <hip/hip_runtime.h>
#include <hip/hip_fp16.h>

// GraphSAGE 2-layer. CSR via bucketed two-phase build; degrees + row-pointers
// derived IN-BUCKET with LDS counters; bucket-scan computed locally per block
// (no scan dispatch). Wave-gather aggregation (round-9 verified versions),
// fp16 MFMA GEMMs (fp32 accum).
// out = SAGE2( relu( SAGE1(x) ) ), SAGE(x) = meanagg(x)@W_l + x@W_r + b
// Layer 2 linearity: meanagg(h)@W2_l == meanagg(h@W2_l) -> gather 64 vals/edge.
// Requires N <= 65536 (nper<=256, src fits in u32>>8 packing). N=50000 here.
// NOTE round-10 bisect: uint2 sub-split gathers REVERTED (prime suspect for
// the 0.0918 failure); vectorized convert + local scans kept.

typedef _Float16 half8 __attribute__((ext_vector_type(8)));
typedef float floatx4 __attribute__((ext_vector_type(4)));

#define NB 256        // buckets
#define PA 320        // partition phase-A blocks
#define HB 320        // histogram chunks (fused into prep)

// ---------- fused: fp16 convert (vectorized) + weight packing + bucket histogram ----------
// Ah row (256 halves): [0:128] = inv*meanagg (by agg128h), [128:256] = fp16(x)
// Bp layout: Bp[((kt*8+nrep)*64+lane)*8+j] = B[kt*32+(lane>>4)*8+j][nrep*16+(lane&15)]
__global__ __launch_bounds__(256) void prep_hist_kernel(const float* __restrict__ x,
                                                        const float* __restrict__ W1l, const float* __restrict__ W1r,
                                                        const float* __restrict__ W2l, const float* __restrict__ W2r,
                                                        _Float16* __restrict__ Ah,
                                                        _Float16* __restrict__ Bp1, _Float16* __restrict__ Bp2,
                                                        const int* __restrict__ dst, int* __restrict__ ghist,
                                                        int N, int E, int nper) {
    __shared__ int lh[NB];
    int nconv = (N * 16 + 255) / 256;   // 8 floats per thread
    int b = blockIdx.x;
    int tid = threadIdx.x;
    if (b < nconv) {
        int i = b * 256 + tid;
        if (i < N * 16) {
            int row = i >> 4, c = i & 15;
            const float4* xp = (const float4*)x;
            float4 v0 = xp[(size_t)row * 32 + c * 2];
            float4 v1 = xp[(size_t)row * 32 + c * 2 + 1];
            __half2 h0 = __floats2half2_rn(v0.x, v0.y);
            __half2 h1 = __floats2half2_rn(v0.z, v0.w);
            __half2 h2 = __floats2half2_rn(v1.x, v1.y);
            __half2 h3 = __floats2half2_rn(v1.z, v1.w);
            uint4 o;
            o.x = *(const uint*)&h0; o.y = *(const uint*)&h1;
            o.z = *(const uint*)&h2; o.w = *(const uint*)&h3;
            *(uint4*)(Ah + (size_t)row * 256 + 128 + c * 8) = o;
        }
    } else if (b < nconv + 128) {
        int t = (b - nconv) * 256 + tid;   // 32768 total
        int j = t & 7, lane = (t >> 3) & 63, nrep = (t >> 9) & 7, kt = t >> 12;
        int k = kt * 32 + ((lane >> 4) * 8) + j;
        int col = nrep * 16 + (lane & 15);
        float v = (k < 128) ? W1l[k * 128 + col] : W1r[(k - 128) * 128 + col];
        Bp1[t] = (_Float16)v;
    } else if (b < nconv + 192) {
        int t = (b - nconv - 128) * 256 + tid;   // 16384 total
        int j = t & 7, lane = (t >> 3) & 63, nrep = (t >> 9) & 7, kt = t >> 12;
        int k = kt * 32 + ((lane >> 4) * 8) + j;
        int col = nrep * 16 + (lane & 15);
        float v = (col < 64) ? W2l[k * 64 + col] : W2r[k * 64 + (col - 64)];
        Bp2[t] = (_Float16)v;
    } else {
        // bucket histogram over a chunk of edges (LDS hist -> one global add/bin)
        int hb = b - nconv - 192;             // 0..HB-1
        lh[tid] = 0;
        __syncthreads();
        int chunk = (E + HB - 1) / HB;
        int e0 = hb * chunk, e1 = min(e0 + chunk, E);
        for (int e = e0 + tid; e < e1; e += 256) atomicAdd(&lh[dst[e] / nper], 1);
        __syncthreads();
        int c = lh[tid];
        if (c) atomicAdd(&ghist[tid], c);
    }
}

// ---------- phase A: partition edges into bucket segments ----------
// Local exclusive scan of ghist (deterministic, identical in all blocks);
// bcur is a zero-initialized RELATIVE cursor. bek[pos] = (src<<8)|(dst-b*nper).
__global__ __launch_bounds__(256) void partA_kernel(const int* __restrict__ src, const int* __restrict__ dst,
                                                    const int* __restrict__ ghist, int* __restrict__ bcur,
                                                    unsigned int* __restrict__ bek,
                                                    int E, int nper) {
    __shared__ int cnt[NB], base[NB], cur[NB];
    __shared__ int ws[4], wo[4];
    int tid = threadIdx.x;
    // local scan of ghist -> excl (register)
    int v = ghist[tid];
    int lane = tid & 63, wid = tid >> 6;
    int s = v;
#pragma unroll
    for (int off = 1; off < 64; off <<= 1) { int t = __shfl_up(s, off); if (lane >= off) s += t; }
    if (lane == 63) ws[wid] = s;
    cnt[tid] = 0; cur[tid] = 0;
    __syncthreads();
    if (tid == 0) { int a = 0; for (int w = 0; w < 4; ++w) { wo[w] = a; a += ws[w]; } }
    __syncthreads();
    int excl = s + wo[wid] - v;
    int chunk = (E + PA - 1) / PA;
    int e0 = blockIdx.x * chunk;
    int e1 = min(e0 + chunk, E);
    for (int e = e0 + tid; e < e1; e += 256) {
        int d = dst[e];
        atomicAdd(&cnt[d / nper], 1);
    }
    __syncthreads();
    int c = cnt[tid];
    base[tid] = excl + ((c > 0) ? atomicAdd(&bcur[tid], c) : 0);
    __syncthreads();
    for (int e = e0 + tid; e < e1; e += 256) {
        int d = dst[e];
        int b = d / nper;
        int pos = base[b] + atomicAdd(&cur[b], 1);
        bek[pos] = ((unsigned int)src[e] << 8) | (unsigned int)(d - b * nper);
    }
}

// ---------- phase B: local ghist scan -> segment bounds; per-bucket degree
//            count (LDS) + local scan -> rp/inv; scatter to csr ----------
__global__ __launch_bounds__(256) void partB2_kernel(const unsigned int* __restrict__ bek,
                                                     const int* __restrict__ ghist,
                                                     int* __restrict__ rp, float* __restrict__ inv,
                                                     int* __restrict__ csr, int N, int nper) {
    __shared__ int gh[NB], exg[NB];
    __shared__ int lcnt[256], excl[256], cur[256];
    __shared__ int ws[4], wo[4];
    int k = blockIdx.x;
    int lo = k * nper;
    int hi = min(lo + nper, N);
    int cntN = hi - lo;
    if (cntN <= 0) return;   // uniform per block
    int tid = threadIdx.x;
    int lane = tid & 63, wid = tid >> 6;
    // scan 1: ghist -> exg (segment bounds)
    int v = ghist[tid];
    gh[tid] = v;
    int s = v;
#pragma unroll
    for (int off = 1; off < 64; off <<= 1) { int t = __shfl_up(s, off); if (lane >= off) s += t; }
    if (lane == 63) ws[wid] = s;
    lcnt[tid] = 0; cur[tid] = 0;
    __syncthreads();
    if (tid == 0) { int a = 0; for (int w = 0; w < 4; ++w) { wo[w] = a; a += ws[w]; } }
    __syncthreads();
    exg[tid] = s + wo[wid] - v;
    __syncthreads();
    int ebeg = exg[k], eend = ebeg + gh[k];
    // pass 1: per-node degree within bucket
    for (int j = ebeg + tid; j < eend; j += 256)
        atomicAdd(&lcnt[bek[j] & 0xffu], 1);
    __syncthreads();
    // scan 2: lcnt -> excl (locs >= cntN are zero)
    int v2 = lcnt[tid];
    int s2 = v2;
#pragma unroll
    for (int off = 1; off < 64; off <<= 1) { int t = __shfl_up(s2, off); if (lane >= off) s2 += t; }
    if (lane == 63) ws[wid] = s2;
    __syncthreads();
    if (tid == 0) { int a = 0; for (int w = 0; w < 4; ++w) { wo[w] = a; a += ws[w]; } }
    __syncthreads();
    excl[tid] = s2 + wo[wid] - v2;
    __syncthreads();
    // rp / inv (rp[hi] double-written by neighbor bucket with same value)
    if (tid <= cntN) {
        int node = lo + tid;
        if (node <= N) rp[node] = ebeg + excl[tid];
        if (tid < cntN) inv[node] = 1.0f / fmaxf((float)lcnt[tid], 1.0f);
    }
    // pass 2: scatter src ids into csr
    for (int j = ebeg + tid; j < eend; j += 256) {
        unsigned int u = bek[j];
        int loc = (int)(u & 0xffu);
        int pos = ebeg + excl[loc] + atomicAdd(&cur[loc], 1);
        csr[pos] = (int)(u >> 8);
    }
}

// ---------- gather aggregation (round-9 verified; fp16 payload, fp32 accum, 8-deep ILP) ----------
__global__ __launch_bounds__(256) void agg128h_kernel(const int* __restrict__ rp, const int* __restrict__ ci,
                                                      _Float16* __restrict__ Ah,
                                                      const float* __restrict__ inv, int N) {
    int node = (blockIdx.x * 256 + threadIdx.x) >> 6;
    int lane = threadIdx.x & 63;
    if (node >= N) return;
    int beg = rp[node], end = rp[node + 1];
    const uint* xu = (const uint*)Ah;   // half2 units; row = 128 units, x-part at +64
    float2 acc = make_float2(0.f, 0.f);
    for (int base = beg; base < end; base += 64) {
        int idx = base + lane;
        int sv = (idx < end) ? ci[idx] : 0;
        int cnt = min(64, end - base);
        int j = 0;
        for (; j + 8 <= cnt; j += 8) {
            uint u[8];
#pragma unroll
            for (int w = 0; w < 8; ++w) {
                int s = __shfl(sv, j + w);
                u[w] = xu[(size_t)s * 128 + 64 + lane];
            }
#pragma unroll
            for (int w = 0; w < 8; ++w) {
                float2 f = __half22float2(*(const __half2*)&u[w]);
                acc.x += f.x; acc.y += f.y;
            }
        }
        for (; j + 4 <= cnt; j += 4) {
            uint u[4];
#pragma unroll
            for (int w = 0; w < 4; ++w) {
                int s = __shfl(sv, j + w);
                u[w] = xu[(size_t)s * 128 + 64 + lane];
            }
#pragma unroll
            for (int w = 0; w < 4; ++w) {
                float2 f = __half22float2(*(const __half2*)&u[w]);
                acc.x += f.x; acc.y += f.y;
            }
        }
        for (; j < cnt; ++j) {
            int s = __shfl(sv, j);
            uint u = xu[(size_t)s * 128 + 64 + lane];
            float2 f = __half22float2(*(const __half2*)&u);
            acc.x += f.x; acc.y += f.y;
        }
    }
    float iv = inv[node];
    __half2 o = __floats2half2_rn(acc.x * iv, acc.y * iv);
    ((uint*)Ah)[(size_t)node * 128 + lane] = *(const uint*)&o;
}

__global__ __launch_bounds__(256) void agg64h_kernel(const int* __restrict__ rp, const int* __restrict__ ci,
                                                     const _Float16* __restrict__ hl,
                                                     const float* __restrict__ inv,
                                                     float* __restrict__ out, int N) {
    int node = (blockIdx.x * 256 + threadIdx.x) >> 5;
    int sl = threadIdx.x & 31;
    if (node >= N) return;
    int beg = rp[node], end = rp[node + 1];
    const uint* hu = (const uint*)hl;   // 32 half2 per row
    float2 acc = make_float2(0.f, 0.f);
    for (int base = beg; base < end; base += 32) {
        int idx = base + sl;
        int sv = (idx < end) ? ci[idx] : 0;
        int cnt = min(32, end - base);
        int j = 0;
        for (; j + 8 <= cnt; j += 8) {
            uint u[8];
#pragma unroll
            for (int w = 0; w < 8; ++w) {
                int s = __shfl(sv, j + w, 32);
                u[w] = hu[(size_t)s * 32 + sl];
            }
#pragma unroll
            for (int w = 0; w < 8; ++w) {
                float2 f = __half22float2(*(const __half2*)&u[w]);
                acc.x += f.x; acc.y += f.y;
            }
        }
        for (; j + 4 <= cnt; j += 4) {
            uint u[4];
#pragma unroll
            for (int w = 0; w < 4; ++w) {
                int s = __shfl(sv, j + w, 32);
                u[w] = hu[(size_t)s * 32 + sl];
            }
#pragma unroll
            for (int w = 0; w < 4; ++w) {
                float2 f = __half22float2(*(const __half2*)&u[w]);
                acc.x += f.x; acc.y += f.y;
            }
        }
        for (; j < cnt; ++j) {
            int s = __shfl(sv, j, 32);
            uint u = hu[(size_t)s * 32 + sl];
            float2 f = __half22float2(*(const __half2*)&u);
            acc.x += f.x; acc.y += f.y;
        }
    }
    float iv = inv[node];
    float2* op = (float2*)(out + (size_t)node * 64 + sl * 2);
    float2 cur = *op;
    cur.x += iv * acc.x;
    cur.y += iv * acc.y;
    *op = cur;
}

// ---------- MFMA GEMMs ----------
__global__ __launch_bounds__(256) void gemm1_mfma(const _Float16* __restrict__ Ah,
                                                  const _Float16* __restrict__ Bp,
                                                  const float* __restrict__ b1,
                                                  _Float16* __restrict__ hh, int N) {
    int wid = threadIdx.x >> 6, lane = threadIdx.x & 63;
    int r = lane & 15, q = lane >> 4;
    int rowbase = blockIdx.x * 128 + wid * 32;
    size_t ra = (size_t)min(rowbase + r, N - 1);
    size_t rb = (size_t)min(rowbase + 16 + r, N - 1);
    const half8* B8 = (const half8*)Bp;

    floatx4 acc[2][8];
#pragma unroll
    for (int m = 0; m < 2; ++m)
#pragma unroll
        for (int n = 0; n < 8; ++n) acc[m][n] = (floatx4){0.f, 0.f, 0.f, 0.f};

#pragma unroll
    for (int kt = 0; kt < 8; ++kt) {
        int k0 = kt * 32 + q * 8;
        half8 a0 = *(const half8*)(Ah + ra * 256 + k0);
        half8 a1 = *(const half8*)(Ah + rb * 256 + k0);
#pragma unroll
        for (int n = 0; n < 8; ++n) {
            half8 bf = B8[(kt * 8 + n) * 64 + lane];
            acc[0][n] = __builtin_amdgcn_mfma_f32_16x16x32_f16(a0, bf, acc[0][n], 0, 0, 0);
            acc[1][n] = __builtin_amdgcn_mfma_f32_16x16x32_f16(a1, bf, acc[1][n], 0, 0, 0);
        }
    }
    float bias[8];
#pragma unroll
    for (int n = 0; n < 8; ++n) bias[n] = b1[n * 16 + r];
#pragma unroll
    for (int m = 0; m < 2; ++m)
#pragma unroll
        for (int reg = 0; reg < 4; ++reg) {
            int row = rowbase + m * 16 + q * 4 + reg;
            if (row < N) {
                _Float16* p = hh + (size_t)row * 128 + r;
#pragma unroll
                for (int n = 0; n < 8; ++n)
                    p[n * 16] = (_Float16)fmaxf(acc[m][n][reg] + bias[n], 0.f);
            }
        }
}

__global__ __launch_bounds__(256) void gemm2_mfma(const _Float16* __restrict__ hh,
                                                  const _Float16* __restrict__ Bp,
                                                  const float* __restrict__ b2,
                                                  _Float16* __restrict__ hl,
                                                  float* __restrict__ outp, int N) {
    int wid = threadIdx.x >> 6, lane = threadIdx.x & 63;
    int r = lane & 15, q = lane >> 4;
    int rowbase = blockIdx.x * 128 + wid * 32;
    size_t ra = (size_t)min(rowbase + r, N - 1);
    size_t rb = (size_t)min(rowbase + 16 + r, N - 1);
    const half8* B8 = (const half8*)Bp;

    floatx4 acc[2][8];
#pragma unroll
    for (int m = 0; m < 2; ++m)
#pragma unroll
        for (int n = 0; n < 8; ++n) acc[m][n] = (floatx4){0.f, 0.f, 0.f, 0.f};

#pragma unroll
    for (int kt = 0; kt < 4; ++kt) {
        int k0 = kt * 32 + q * 8;
        half8 a0 = *(const half8*)(hh + ra * 128 + k0);
        half8 a1 = *(const half8*)(hh + rb * 128 + k0);
#pragma unroll
        for (int n = 0; n < 8; ++n) {
            half8 bf = B8[(kt * 8 + n) * 64 + lane];
            acc[0][n] = __builtin_amdgcn_mfma_f32_16x16x32_f16(a0, bf, acc[0][n], 0, 0, 0);
            acc[1][n] = __builtin_amdgcn_mfma_f32_16x16x32_f16(a1, bf, acc[1][n], 0, 0, 0);
        }
    }
    float bias[4];
#pragma unroll
    for (int n = 0; n < 4; ++n) bias[n] = b2[n * 16 + r];
#pragma unroll
    for (int m = 0; m < 2; ++m)
#pragma unroll
        for (int reg = 0; reg < 4; ++reg) {
            int row = rowbase + m * 16 + q * 4 + reg;
            if (row < N) {
                _Float16* ph = hl + (size_t)row * 64 + r;
                float* po = outp + (size_t)row * 64 + r;
#pragma unroll
                for (int n = 0; n < 4; ++n)
                    ph[n * 16] = (_Float16)acc[m][n][reg];
#pragma unroll
                for (int n = 0; n < 4; ++n)
                    po[n * 16] = acc[m][n + 4][reg] + bias[n];
            }
        }
}

extern "C" void kernel_launch(void* const* d_in, const int* in_sizes, int n_in,
                              void* d_out, int out_size, void* d_ws, size_t ws_size,
                              hipStream_t stream) {
    const float* x   = (const float*)d_in[0];
    const int*   ei  = (const int*)d_in[1];
    const float* W1l = (const float*)d_in[2];
    const float* W1r = (const float*)d_in[3];
    const float* b1  = (const float*)d_in[4];
    const float* W2l = (const float*)d_in[5];
    const float* W2r = (const float*)d_in[6];
    const float* b2  = (const float*)d_in[7];
    float* out = (float*)d_out;

    const int N = in_sizes[0] / 128;   // 50000
    const int E = in_sizes[1] / 2;     // 640000
    const int* srcv = ei;
    const int* dstv = ei + E;
    const int nper = (N + NB - 1) / NB;   // 196 (requires <= 256)

    // workspace layout
    _Float16* Ah  = (_Float16*)d_ws;                      // N*256 halves
    _Float16* hh  = Ah + (size_t)N * 256;                 // N*128 halves
    _Float16* hl  = hh + (size_t)N * 128;                 // N*64 halves
    _Float16* Bp1 = hl + (size_t)N * 64;                  // 32768 halves
    _Float16* Bp2 = Bp1 + 32768;                          // 16384 halves
    float* inv  = (float*)(Bp2 + 16384);                  // N floats
    int*   rp   = (int*)(inv + N);                        // N+1
    int*   csr  = rp + (N + 1);                           // E
    unsigned int* bek = (unsigned int*)(csr + E);         // E
    int*   ghist = (int*)(bek + E);                       // NB
    int*   bcur  = ghist + NB;                            // NB (relative, zeroed)

    hipMemsetAsync(ghist, 0, (size_t)(2 * NB) * sizeof(int), stream);   // ghist + bcur

    int nconv = (N * 16 + 255) / 256;                     // 3125
    prep_hist_kernel<<<nconv + 192 + HB, 256, 0, stream>>>(x, W1l, W1r, W2l, W2r,
                                                           Ah, Bp1, Bp2, dstv, ghist, N, E, nper);

    partA_kernel<<<PA, 256, 0, stream>>>(srcv, dstv, ghist, bcur, bek, E, nper);
    partB2_kernel<<<NB, 256, 0, stream>>>(bek, ghist, rp, inv, csr, N, nper);

    // layer 1
    agg128h_kernel<<<(N * 64 + 255) / 256, 256, 0, stream>>>(rp, csr, Ah, inv, N);
    int nb = (N + 127) / 128;
    gemm1_mfma<<<nb, 256, 0, stream>>>(Ah, Bp1, b1, hh, N);

    // layer 2
    gemm2_mfma<<<nb, 256, 0, stream>>>(hh, Bp2, b2, hl, out, N);
    agg64h_kernel<<<(N * 32 + 255) / 256, 256, 0, stream>>>(rp, csr, hl, inv, out, N);
}